// Round 3
// baseline (219.184 us; speedup 1.0000x reference)
//
#include <hip/hip_runtime.h>

#define CIN    128
#define COUT   256
#define Hh     112
#define Ww     112
#define HW     12544          // 112*112
#define NBATCH 8
#define NPIX   (NBATCH*HW)    // 100352
#define KD     (CIN*9)        // 1152
#define PH     114            // padded H/W
#define PPIX   (NBATCH*PH*PH) // padded pixel count

typedef __bf16         v8bf __attribute__((ext_vector_type(8)));
typedef float          v4f  __attribute__((ext_vector_type(4)));

__device__ __forceinline__ unsigned short f2bf(float f) {
  unsigned int u = __float_as_uint(f);
  u += 0x7FFFu + ((u >> 16) & 1u);   // round-to-nearest-even
  return (unsigned short)(u >> 16);
}

__device__ __forceinline__ void gl_lds16(const void* g, void* l) {
  __builtin_amdgcn_global_load_lds(
      (const __attribute__((address_space(1))) void*)g,
      (__attribute__((address_space(3))) void*)l, 16, 0, 0);
}

// ---------------------------------------------------------------------------
// Kernel PRE: unchanged (fused transpose + sq + border zero + weight pack)
// ---------------------------------------------------------------------------
#define USS 130   // ushort-stride of LDS pixel row (128 + 2 pad)
__global__ __launch_bounds__(256) void k_pre(
    const float* __restrict__ x, const float* __restrict__ w,
    unsigned short* __restrict__ xbp, unsigned short* __restrict__ wpk,
    float* __restrict__ sq)
{
  __shared__ unsigned short US[112 * USS];   // 29,120 B
  __shared__ float sqp[112 * 4];

  int tid = threadIdx.x;
  int bid = blockIdx.x;

  if (bid >= NBATCH * PH) {
    int t = (bid - NBATCH * PH) * 2048 + tid * 8;
#pragma unroll
    for (int i = 0; i < 8; ++i) {
      int idx = t + i;
      int o  = idx / KD;
      int rr = idx - o * KD;
      int kk = rr >> 7;
      int c  = rr & 127;
      wpk[idx] = f2bf(w[(size_t)o * KD + c * 9 + kk]);
    }
    return;
  }

  int b  = bid / PH;
  int py = bid - b * PH;
  unsigned int* dstrow = (unsigned int*)xbp +
      (size_t)(b * PH + py) * PH * (CIN / 2);

  if (py == 0 || py == PH - 1) {
    uint4 z = {0, 0, 0, 0};
    for (int h = tid; h < PH * (CIN / 8); h += 256)
      *(uint4*)(dstrow + h * 4) = z;
    return;
  }

  int oy  = py - 1;
  int l   = tid & 63;
  int wid = tid >> 6;
  const float* xp = x + (size_t)b * CIN * HW + (size_t)oy * Ww;
  bool valid = l < 56;

  float a0 = 0.0f, a1 = 0.0f;
#pragma unroll
  for (int it = 0; it < 32; ++it) {
    int c = wid * 32 + it;
    float vx = 0.0f, vy = 0.0f;
    if (valid) {
      float2 v = *(const float2*)(xp + (size_t)c * HW + 2 * l);
      vx = v.x; vy = v.y;
    }
    a0 += vx * vx;
    a1 += vy * vy;
    if (valid) {
      US[(2 * l) * USS + c]     = f2bf(vx);
      US[(2 * l + 1) * USS + c] = f2bf(vy);
    }
  }
  if (valid) { sqp[(2 * l) * 4 + wid] = a0; sqp[(2 * l + 1) * 4 + wid] = a1; }
  __syncthreads();

  if (tid < 112) {
    float s = sqp[tid * 4] + sqp[tid * 4 + 1] + sqp[tid * 4 + 2] + sqp[tid * 4 + 3];
    sq[(size_t)b * HW + (size_t)oy * Ww + tid] = s;
  }

  unsigned int* dst = dstrow + (CIN / 2);
  for (int h = tid; h < 112 * 16; h += 256) {
    int px = h >> 4, part = h & 15;
    const unsigned short* s = &US[px * USS + part * 8];
    uint4 vv;
    vv.x = *(const unsigned int*)(s + 0);
    vv.y = *(const unsigned int*)(s + 2);
    vv.z = *(const unsigned int*)(s + 4);
    vv.w = *(const unsigned int*)(s + 6);
    *(uint4*)(dst + h * 4) = vv;
  }

  if (tid < 32) {
    uint4 z = {0, 0, 0, 0};
    int px   = (tid >> 4) ? (PH - 1) : 0;
    int part = tid & 15;
    *(uint4*)(dstrow + px * (CIN / 2) + part * 4) = z;
  }
}

// ---------------------------------------------------------------------------
// Kernel C: 256x256 tile, BK=64, 512 threads (8 waves, 2M x 4N), double-
// buffered LDS (128 KiB) with counted-vmcnt pipeline (T3/T4): per K-tile,
// compute(cur) -> barrier -> issue stage(t+2 -> cur) -> vmcnt(8) (waits only
// tile t+1's loads; t+2's stay in flight across the next tile's MFMAs;
// never drained to 0 in the loop) -> barrier. Raw s_barrier + sched_barrier
// fences; NO __syncthreads in the loop (it would emit vmcnt(0)).
// T5 setprio around MFMA clusters. Epilogue: 4 slab passes of 64 rows.
// ---------------------------------------------------------------------------
__device__ __forceinline__ void conv_tile(
    unsigned short* Ab, unsigned short* Bb,
    int t, bool do_stage,
    v4f (&acc)[8][4], const int (&pb)[4],
    const unsigned short* __restrict__ asrc,
    const unsigned short* __restrict__ xbp,
    int wm, int wn, int quad, int l16, int wid)
{
#pragma unroll
  for (int h = 0; h < 2; ++h) {
    v8bf bfr[4];
    int cch = (h * 4 + quad) ^ (l16 & 7);
#pragma unroll
    for (int nt = 0; nt < 4; ++nt)
      bfr[nt] = *(const v8bf*)&Bb[(wn * 64 + nt * 16 + l16) * 64 + cch * 8];
#pragma unroll
    for (int mh = 0; mh < 2; ++mh) {
      v8bf af[4];
#pragma unroll
      for (int m2 = 0; m2 < 4; ++m2)
        af[m2] = *(const v8bf*)&Ab[(wm * 128 + (mh * 4 + m2) * 16 + l16) * 64 + cch * 8];
      __builtin_amdgcn_s_setprio(1);
#pragma unroll
      for (int m2 = 0; m2 < 4; ++m2)
#pragma unroll
        for (int nt = 0; nt < 4; ++nt)
          acc[mh * 4 + m2][nt] = __builtin_amdgcn_mfma_f32_16x16x32_bf16(
              af[m2], bfr[nt], acc[mh * 4 + m2][nt], 0, 0, 0);
      __builtin_amdgcn_s_setprio(0);
    }
  }
  // ---- handoff: all waves done reading (Ab,Bb) ----
  __builtin_amdgcn_sched_barrier(0);
  __builtin_amdgcn_s_barrier();
  __builtin_amdgcn_sched_barrier(0);
  if (do_stage) {
    int t2 = t + 2;
    int kk = t2 >> 1;
    int kh = kk / 3, kw = kk - 3 * kh;
    int soff = (kh * PH + kw) * CIN + (t2 & 1) * 64;
#pragma unroll
    for (int jj = 0; jj < 4; ++jj)
      gl_lds16(asrc + (size_t)jj * 64 * KD + t2 * 64,
               &Ab[(jj * 64 + wid * 8) * 64]);
#pragma unroll
    for (int jj = 0; jj < 4; ++jj)
      gl_lds16(xbp + pb[jj] + soff,
               &Bb[(jj * 64 + wid * 8) * 64]);
    asm volatile("s_waitcnt vmcnt(8)" ::: "memory");   // t+1 landed; t+2 flies
  } else {
    asm volatile("s_waitcnt vmcnt(0)" ::: "memory");   // tail drain
  }
  __builtin_amdgcn_sched_barrier(0);
  __builtin_amdgcn_s_barrier();
  __builtin_amdgcn_sched_barrier(0);
}

#define SLAB2 260   // fp32 slab stride: 16B-aligned, quads 2-way banks max
__global__ __launch_bounds__(512, 2) void k_conv(
    const unsigned short* __restrict__ wp,
    const unsigned short* __restrict__ xbp,
    const float* __restrict__ sq,
    const float* __restrict__ bias,
    float* __restrict__ out)
{
  extern __shared__ __align__(16) char smem[];         // 131,072 B dynamic
  unsigned short* As0 = (unsigned short*)smem;         // [256][64]
  unsigned short* Bs0 = As0 + 256 * 64;
  unsigned short* As1 = Bs0 + 256 * 64;
  unsigned short* Bs1 = As1 + 256 * 64;
  float* slab = (float*)smem;                          // [64][SLAB2]

  int tid  = threadIdx.x;
  int lane = tid & 63;
  int wid  = tid >> 6;          // 0..7
  int wm   = wid >> 2;          // 0..1  (M half)
  int wn   = wid & 3;           // 0..3  (N quarter)
  int quad = lane >> 4;
  int l16  = lane & 15;

  // T1: 392 = 8*49, bijective XCD swizzle
  int L  = blockIdx.x;
  int bn = (L & 7) * 49 + (L >> 3);
  int nbase = bn * 256;

  // staging map: row = tid>>3 (+64/issue), chunk = (tid&7) XOR row&7
  int srow = tid >> 3;          // 0..63
  int g16  = (tid & 7) ^ (srow & 7);

  const unsigned short* asrc = wp + (size_t)srow * KD + g16 * 8;

  int pb[4];
#pragma unroll
  for (int jj = 0; jj < 4; ++jj) {
    int n  = nbase + jj * 64 + srow;
    int b  = n / HW;  int r  = n - b * HW;
    int oy = r / Ww;  int ox = r - oy * Ww;
    pb[jj] = ((b * PH + oy) * PH + ox) * CIN + g16 * 8;
  }

  v4f acc[8][4];
#pragma unroll
  for (int mt = 0; mt < 8; ++mt)
#pragma unroll
    for (int nt = 0; nt < 4; ++nt)
#pragma unroll
      for (int q = 0; q < 4; ++q) acc[mt][nt][q] = 0.0f;

  // ---- prologue: stage tiles 0 (buf0) and 1 (buf1); wait tile 0 only ----
#pragma unroll
  for (int jj = 0; jj < 4; ++jj)
    gl_lds16(asrc + (size_t)jj * 64 * KD, &As0[(jj * 64 + wid * 8) * 64]);
#pragma unroll
  for (int jj = 0; jj < 4; ++jj)
    gl_lds16(xbp + pb[jj], &Bs0[(jj * 64 + wid * 8) * 64]);
#pragma unroll
  for (int jj = 0; jj < 4; ++jj)
    gl_lds16(asrc + (size_t)jj * 64 * KD + 64, &As1[(jj * 64 + wid * 8) * 64]);
#pragma unroll
  for (int jj = 0; jj < 4; ++jj)
    gl_lds16(xbp + pb[jj] + 64, &Bs1[(jj * 64 + wid * 8) * 64]);
  asm volatile("s_waitcnt vmcnt(8)" ::: "memory");     // tile 0 resident
  __builtin_amdgcn_sched_barrier(0);
  __builtin_amdgcn_s_barrier();
  __builtin_amdgcn_sched_barrier(0);

  // ---- main loop: 18 K-tiles ----
  for (int i = 0; i < 8; ++i) {
    conv_tile(As0, Bs0, 2 * i,     true, acc, pb, asrc, xbp, wm, wn, quad, l16, wid);
    conv_tile(As1, Bs1, 2 * i + 1, true, acc, pb, asrc, xbp, wm, wn, quad, l16, wid);
  }
  conv_tile(As0, Bs0, 16, false, acc, pb, asrc, xbp, wm, wn, quad, l16, wid);
  conv_tile(As1, Bs1, 17, false, acc, pb, asrc, xbp, wm, wn, quad, l16, wid);

  // ---- epilogue ----------------------------------------------------------
  // fused invnorm (epilogue placement, proven round 2)
  float invv[4];
#pragma unroll
  for (int nt = 0; nt < 4; ++nt) {
    int n  = nbase + wn * 64 + nt * 16 + l16;
    int b  = n / HW;  int r  = n - b * HW;
    int oy = r / Ww;  int ox = r - oy * Ww;
    const float* s = sq + (size_t)b * HW;
    float a2 = 0.0f;
#pragma unroll
    for (int dy = -1; dy <= 1; ++dy) {
      int iy = oy + dy;
      if (iy < 0 || iy >= Hh) continue;
#pragma unroll
      for (int dx = -1; dx <= 1; ++dx) {
        int ix = ox + dx;
        if (ix < 0 || ix >= Ww) continue;
        a2 += s[iy * Ww + ix];
      }
    }
    invv[nt] = 1.0f / fmaxf(sqrtf(a2), 1e-12f);
  }

  int bb = nbase / HW;           // 256 | HW, tile within one batch
  int rr = nbase - bb * HW;
  float* obase = out + (size_t)bb * COUT * HW + rr;

  // 4 passes of 64 output rows through the LDS slab
#pragma unroll
  for (int p = 0; p < 4; ++p) {
    if (p) __syncthreads();
    if (wm == (p >> 1)) {
      int base_mt = (p & 1) * 4;
#pragma unroll
      for (int m2 = 0; m2 < 4; ++m2)
#pragma unroll
        for (int nt = 0; nt < 4; ++nt) {
          int col = wn * 64 + nt * 16 + l16;
#pragma unroll
          for (int reg = 0; reg < 4; ++reg)
            slab[(m2 * 16 + quad * 4 + reg) * SLAB2 + col] =
                acc[base_mt + m2][nt][reg] * invv[nt];
        }
    }
    __syncthreads();
    int r  = tid >> 3;           // 0..63
    int o  = p * 64 + r;
    float bv = bias[o];
    float* orow = obase + (size_t)o * HW;
#pragma unroll
    for (int k = 0; k < 8; ++k) {
      int c4 = (tid & 7) * 4 + k * 32;
      v4f v = *(const v4f*)&slab[r * SLAB2 + c4];
      v4f r2;
#pragma unroll
      for (int q = 0; q < 4; ++q) r2[q] = v[q] + bv;
      *(v4f*)(orow + c4) = r2;   // 8 lanes -> 128B contiguous
    }
  }
}

// ---------------------------------------------------------------------------
extern "C" void kernel_launch(void* const* d_in, const int* in_sizes, int n_in,
                              void* d_out, int out_size, void* d_ws, size_t ws_size,
                              hipStream_t stream) {
  const float* x    = (const float*)d_in[0];  // [8,128,112,112]
  const float* w    = (const float*)d_in[1];  // [256,128,3,3]
  const float* bias = (const float*)d_in[2];  // [256]
  float* out        = (float*)d_out;          // [8,256,112,112]

  char* ws = (char*)d_ws;
  unsigned short* xbp = (unsigned short*)ws;                   // 26,615,808 B
  size_t off = (size_t)PPIX * CIN * 2;
  unsigned short* wpk = (unsigned short*)(ws + off);           // 589,824 B
  off += (size_t)COUT * KD * 2;
  float* sq = (float*)(ws + off);                              // 401,408 B

  static bool attr_done = false;
  if (!attr_done) {
    hipFuncSetAttribute((const void*)k_conv,
                        hipFuncAttributeMaxDynamicSharedMemorySize, 131072);
    attr_done = true;
  }

  k_pre<<<NBATCH * PH + (COUT * KD) / 2048, 256, 0, stream>>>(x, w, xbp, wpk, sq);
  k_conv<<<392, 512, 131072, stream>>>(wpk, xbp, sq, bias, out);
}